// Round 1
// baseline (609.561 us; speedup 1.0000x reference)
//
#include <hip/hip_runtime.h>
#include <hip/hip_bf16.h>
#include <stdint.h>
#include <math.h>

#define AS1 __attribute__((address_space(1)))
#define AS3 __attribute__((address_space(3)))

typedef __bf16 bf16_t;
typedef __bf16 bf16x8 __attribute__((ext_vector_type(8)));
typedef float f32x4 __attribute__((ext_vector_type(4)));

static constexpr int B_ = 16, N_ = 616, C_ = 768, H_ = 12, HD = 64, HID = 3072;
static constexpr int NP = 640;            // padded seq len (multiple of 64)
static constexpr int M_ALL = B_ * N_;     // 9856
static constexpr int NT = 40, NI = 576;   // text/image tokens per batch row
static constexpr int MT = B_ * NT;        // 640
static constexpr int MI = B_ * NI;        // 9216

// ---- global -> LDS direct copy, 16B per lane. LDS dest must be wave-uniform
// base; HW adds lane*16. Integer-cast route: low 32 bits of a generic LDS
// pointer are the LDS byte offset on gfx9+.
__device__ __forceinline__ void gl_lds16(const void* g, void* l) {
  __builtin_amdgcn_global_load_lds((const AS1 void*)(uintptr_t)g,
                                   (AS3 void*)(uint32_t)(uintptr_t)l, 16, 0, 0);
}

__device__ __forceinline__ f32x4 mfma16(bf16x8 a, bf16x8 b, f32x4 c) {
  return __builtin_amdgcn_mfma_f32_16x16x32_bf16(a, b, c, 0, 0, 0);
}

// ---------------------------------------------------------------- weight cast
__global__ void cast_f32_bf16(const float* __restrict__ in, bf16_t* __restrict__ out, int n) {
  int i = blockIdx.x * blockDim.x + threadIdx.x;
  int st = gridDim.x * blockDim.x;
  for (; i < n; i += st) out[i] = (bf16_t)in[i];
}

__global__ void zero_f4(float4* __restrict__ p, int n4) {
  int i = blockIdx.x * blockDim.x + threadIdx.x;
  int st = gridDim.x * blockDim.x;
  float4 z = {0.f, 0.f, 0.f, 0.f};
  for (; i < n4; i += st) p[i] = z;
}

// ---------------------------------------------------------------- layernorms
__global__ __launch_bounds__(256) void ln_rows(const float* __restrict__ x,
                                               const float* __restrict__ g,
                                               const float* __restrict__ b,
                                               bf16_t* __restrict__ out) {
  int r = blockIdx.x;
  const float* xr = x + (size_t)r * C_;
  int t = threadIdx.x;
  float v0 = xr[t], v1 = xr[t + 256], v2 = xr[t + 512];
  float s = v0 + v1 + v2, ss = v0 * v0 + v1 * v1 + v2 * v2;
#pragma unroll
  for (int off = 32; off > 0; off >>= 1) { s += __shfl_xor(s, off); ss += __shfl_xor(ss, off); }
  __shared__ float sm[8];
  int w = t >> 6;
  if ((t & 63) == 0) { sm[w] = s; sm[4 + w] = ss; }
  __syncthreads();
  s = sm[0] + sm[1] + sm[2] + sm[3];
  ss = sm[4] + sm[5] + sm[6] + sm[7];
  float mean = s * (1.f / C_);
  float var = ss * (1.f / C_) - mean * mean;
  float ri = rsqrtf(var + 1e-5f);
  bf16_t* orow = out + (size_t)r * C_;
  orow[t]       = (bf16_t)((v0 - mean) * ri * g[t]       + b[t]);
  orow[t + 256] = (bf16_t)((v1 - mean) * ri * g[t + 256] + b[t + 256]);
  orow[t + 512] = (bf16_t)((v2 - mean) * ri * g[t + 512] + b[t + 512]);
}

// LN2 with text/image param select + gather into packed layout:
// packed rows [0,640) = text (b*40+n), [640,9856) = image (640 + b*576 + (n-40))
__global__ __launch_bounds__(256) void ln2_pack(const float* __restrict__ x1,
                                                const float* __restrict__ gt, const float* __restrict__ bt,
                                                const float* __restrict__ gi, const float* __restrict__ bi,
                                                bf16_t* __restrict__ out) {
  int m = blockIdx.x;
  int b_ = m / N_, nn = m - b_ * N_;
  const float* g; const float* bb; int dest;
  if (nn < NT) { dest = b_ * NT + nn; g = gt; bb = bt; }
  else         { dest = MT + b_ * NI + (nn - NT); g = gi; bb = bi; }
  const float* xr = x1 + (size_t)m * C_;
  int t = threadIdx.x;
  float v0 = xr[t], v1 = xr[t + 256], v2 = xr[t + 512];
  float s = v0 + v1 + v2, ss = v0 * v0 + v1 * v1 + v2 * v2;
#pragma unroll
  for (int off = 32; off > 0; off >>= 1) { s += __shfl_xor(s, off); ss += __shfl_xor(ss, off); }
  __shared__ float sm[8];
  int w = t >> 6;
  if ((t & 63) == 0) { sm[w] = s; sm[4 + w] = ss; }
  __syncthreads();
  s = sm[0] + sm[1] + sm[2] + sm[3];
  ss = sm[4] + sm[5] + sm[6] + sm[7];
  float mean = s * (1.f / C_);
  float var = ss * (1.f / C_) - mean * mean;
  float ri = rsqrtf(var + 1e-5f);
  bf16_t* orow = out + (size_t)dest * C_;
  orow[t]       = (bf16_t)((v0 - mean) * ri * g[t]       + bb[t]);
  orow[t + 256] = (bf16_t)((v1 - mean) * ri * g[t + 256] + bb[t + 256]);
  orow[t + 512] = (bf16_t)((v2 - mean) * ri * g[t + 512] + bb[t + 512]);
}

// ---------------------------------------------------------------- GEMM (B^T)
// C[M][Nn] = A[M][K] * Bw[Nn][K]^T, 128x128 tile, BK=64, 4 waves, each wave a
// 64x64 sub-tile of 4x4 16x16 fragments. Epilogue variants via EPI.
struct EpiP {
  const float* bias;   // per-col bias
  const float* bias2;  // v_bias (EPI0)
  const float* gamma;
  const float* xres;   // residual f32
  float* outf;
  bf16_t* ob0;
  bf16_t* ob1;
  bf16_t* ob2;
  int npb, noff;       // EPI3 packed-row mapping
};

template <int EPI>
__global__ __launch_bounds__(256) void gemm_bt(const bf16_t* __restrict__ A,
                                               const bf16_t* __restrict__ Bw,
                                               int K, int Nn, EpiP P) {
  __shared__ bf16_t As[128 * 64];
  __shared__ bf16_t Bs[128 * 64];
  const int tid = threadIdx.x;
  const int lane = tid & 63, w = tid >> 6;
  const int l16 = lane & 15, lq = lane >> 4;
  const int m0 = blockIdx.x * 128, n0 = blockIdx.y * 128;
  const int wm = (w >> 1) * 64, wn = (w & 1) * 64;
  f32x4 acc[4][4] = {};

  for (int k0 = 0; k0 < K; k0 += 64) {
#pragma unroll
    for (int it = 0; it < 4; ++it) {
      int cb = it * 256 + w * 64;
      int c = cb + lane;
      int row = c >> 3, col = (c & 7) << 3;
      gl_lds16(A + (size_t)(m0 + row) * K + (k0 + col), As + cb * 8);
      gl_lds16(Bw + (size_t)(n0 + row) * K + (k0 + col), Bs + cb * 8);
    }
    __syncthreads();
#pragma unroll
    for (int kk = 0; kk < 2; ++kk) {
      bf16x8 av[4], bv[4];
#pragma unroll
      for (int i = 0; i < 4; ++i) {
        av[i] = *(const bf16x8*)(As + (wm + i * 16 + l16) * 64 + kk * 32 + lq * 8);
        bv[i] = *(const bf16x8*)(Bs + (wn + i * 16 + l16) * 64 + kk * 32 + lq * 8);
      }
#pragma unroll
      for (int i = 0; i < 4; ++i)
#pragma unroll
        for (int j = 0; j < 4; ++j)
          acc[i][j] = mfma16(av[i], bv[j], acc[i][j]);
    }
    __syncthreads();
  }

#pragma unroll
  for (int i = 0; i < 4; ++i) {
#pragma unroll
    for (int j = 0; j < 4; ++j) {
#pragma unroll
      for (int r = 0; r < 4; ++r) {
        int m = m0 + wm + i * 16 + lq * 4 + r;     // C/D: row=(lane>>4)*4+reg
        int jc = n0 + wn + j * 16 + l16;           //      col=lane&15   [m89]
        float v = acc[i][j][r];
        if constexpr (EPI == 0) {          // QKV: split/scale/bias, v transposed
          int b_ = m / N_, nn = m - b_ * N_;
          int which = jc / C_;
          int jj = jc - which * C_;
          int hh = jj >> 6, d = jj & 63;
          int bh = b_ * H_ + hh;
          if (which == 0) {
            v = (v + P.bias[jj]) * 0.125f;
            P.ob0[((size_t)bh * NP + nn) * HD + d] = (bf16_t)v;
          } else if (which == 1) {
            P.ob1[((size_t)bh * NP + nn) * HD + d] = (bf16_t)v;
          } else {
            v = v + P.bias2[jj];
            P.ob2[((size_t)bh * HD + d) * NP + nn] = (bf16_t)v;
          }
        } else if constexpr (EPI == 1) {   // proj: x1 = x + gamma1*(o+b)
          size_t idx = (size_t)m * C_ + jc;
          P.outf[idx] = P.xres[idx] + P.gamma[jc] * (v + P.bias[jc]);
        } else if constexpr (EPI == 2) {   // mlp1: gelu(v + b) -> bf16
          float t = v + P.bias[jc];
          float gg = 0.5f * t * (1.f + erff(t * 0.70710678118f));
          P.ob0[(size_t)m * HID + jc] = (bf16_t)gg;
        } else {                           // mlp2: scatter residual to d_out
          int q = m / P.npb, rr = m - q * P.npb;
          int orig = q * N_ + P.noff + rr;
          size_t idx = (size_t)orig * C_ + jc;
          P.outf[idx] = P.xres[idx] + P.gamma[jc] * (v + P.bias[jc]);
        }
      }
    }
  }
}

// ---------------------------------------------------------------- attention
// One block = (q-tile of 64 rows) x (b,h). 4 waves, each owns 16 q-rows.
// Online softmax in registers; V pre-transposed so PV B-operand is K-contig.
__global__ __launch_bounds__(256) void attn_fwd(const bf16_t* __restrict__ qb,
                                                const bf16_t* __restrict__ kb,
                                                const bf16_t* __restrict__ vT,
                                                const float* __restrict__ rel_bias,
                                                bf16_t* __restrict__ o_mat) {
  __shared__ bf16_t qs[64 * 64], ks[64 * 64], vs[64 * 64];
  __shared__ bf16_t ps[4][16 * 64];
  const int tid = threadIdx.x, lane = tid & 63, w = tid >> 6;
  const int l16 = lane & 15, lq = lane >> 4;
  const int qt = blockIdx.x, bh = blockIdx.y;
  const int b_ = bh / H_, h = bh - b_ * H_;
  const int q0 = qt * 64;

  const bf16_t* qsrc = qb + ((size_t)bh * NP + q0) * HD;
#pragma unroll
  for (int it = 0; it < 2; ++it) {
    int cb = it * 256 + w * 64, c = cb + lane;
    gl_lds16(qsrc + c * 8, qs + cb * 8);
  }
  __syncthreads();
  bf16x8 aq[2];
  aq[0] = *(const bf16x8*)(qs + (w * 16 + l16) * 64 + 0 + lq * 8);
  aq[1] = *(const bf16x8*)(qs + (w * 16 + l16) * 64 + 32 + lq * 8);

  float mrun[4], lrun[4];
  f32x4 oacc[4] = {};
#pragma unroll
  for (int r = 0; r < 4; ++r) { mrun[r] = -3e38f; lrun[r] = 0.f; }

  const int qrow_base = q0 + w * 16 + lq * 4;
  const float* biasr = rel_bias + (size_t)h * N_ * N_;

  for (int kt = 0; kt < NP / 64; ++kt) {
    int n0k = kt * 64;
    const bf16_t* ksrc = kb + ((size_t)bh * NP + n0k) * HD;
#pragma unroll
    for (int it = 0; it < 2; ++it) {
      int cb = it * 256 + w * 64, c = cb + lane;
      gl_lds16(ksrc + c * 8, ks + cb * 8);
      int d = c >> 3, kc = (c & 7) << 3;
      gl_lds16(vT + ((size_t)bh * HD + d) * NP + n0k + kc, vs + cb * 8);
    }
    __syncthreads();

    // S strip = Q K^T  (16 x 64)
    f32x4 sf[4];
#pragma unroll
    for (int f = 0; f < 4; ++f) {
      f32x4 z = {};
#pragma unroll
      for (int kk = 0; kk < 2; ++kk) {
        bf16x8 bk = *(const bf16x8*)(ks + (f * 16 + l16) * 64 + kk * 32 + lq * 8);
        z = mfma16(aq[kk], bk, z);
      }
      sf[f] = z;
    }
    // + rel_bias, mask cols >= 616 (select, so pad NaN can never leak)
    float pm[4];
#pragma unroll
    for (int r = 0; r < 4; ++r) pm[r] = -3e38f;
#pragma unroll
    for (int f = 0; f < 4; ++f) {
      int kcol = n0k + f * 16 + l16;
#pragma unroll
      for (int r = 0; r < 4; ++r) {
        int qg = qrow_base + r;
        int qc = qg < N_ ? qg : (N_ - 1);
        float sv = (kcol < N_) ? (sf[f][r] + biasr[(size_t)qc * N_ + kcol]) : -3e38f;
        sf[f][r] = sv;
        pm[r] = fmaxf(pm[r], sv);
      }
    }
#pragma unroll
    for (int off = 1; off < 16; off <<= 1)
#pragma unroll
      for (int r = 0; r < 4; ++r)
        pm[r] = fmaxf(pm[r], __shfl_xor(pm[r], off, 16));

    float alpha[4], lsum[4];
#pragma unroll
    for (int r = 0; r < 4; ++r) {
      float mnew = fmaxf(mrun[r], pm[r]);
      alpha[r] = __expf(mrun[r] - mnew);
      mrun[r] = mnew;
      lsum[r] = 0.f;
    }
#pragma unroll
    for (int f = 0; f < 4; ++f)
#pragma unroll
      for (int r = 0; r < 4; ++r) {
        float p = __expf(sf[f][r] - mrun[r]);
        sf[f][r] = p;
        lsum[r] += p;
      }
#pragma unroll
    for (int off = 1; off < 16; off <<= 1)
#pragma unroll
      for (int r = 0; r < 4; ++r)
        lsum[r] += __shfl_xor(lsum[r], off, 16);
#pragma unroll
    for (int r = 0; r < 4; ++r) lrun[r] = lrun[r] * alpha[r] + lsum[r];
#pragma unroll
    for (int df = 0; df < 4; ++df)
#pragma unroll
      for (int r = 0; r < 4; ++r) oacc[df][r] *= alpha[r];

    // P -> LDS (bf16), relayout C-frag -> A-frag
    bf16_t* psw = ps[w];
#pragma unroll
    for (int f = 0; f < 4; ++f)
#pragma unroll
      for (int r = 0; r < 4; ++r)
        psw[(lq * 4 + r) * 64 + f * 16 + l16] = (bf16_t)sf[f][r];
    __syncthreads();  // make P visible across lanes (conservative)

    // O += P V  : A = P strip [16 x 64], B = vT tile rows (d-major, k-contig)
#pragma unroll
    for (int kk = 0; kk < 2; ++kk) {
      bf16x8 pa = *(const bf16x8*)(psw + l16 * 64 + kk * 32 + lq * 8);
#pragma unroll
      for (int df = 0; df < 4; ++df) {
        bf16x8 bv = *(const bf16x8*)(vs + (df * 16 + l16) * 64 + kk * 32 + lq * 8);
        oacc[df] = mfma16(pa, bv, oacc[df]);
      }
    }
    __syncthreads();
  }

#pragma unroll
  for (int r = 0; r < 4; ++r) {
    int qg = qrow_base + r;
    if (qg < N_) {
      float rl = 1.f / lrun[r];
      size_t orow = ((size_t)(b_ * N_ + qg)) * C_ + h * HD;
#pragma unroll
      for (int df = 0; df < 4; ++df)
        o_mat[orow + df * 16 + l16] = (bf16_t)(oacc[df][r] * rl);
    }
  }
}

// ---------------------------------------------------------------- launch
extern "C" void kernel_launch(void* const* d_in, const int* in_sizes, int n_in,
                              void* d_out, int out_size, void* d_ws, size_t ws_size,
                              hipStream_t stream) {
  const float* x      = (const float*)d_in[0];
  const float* rel    = (const float*)d_in[1];
  const float* ln1_g  = (const float*)d_in[2];
  const float* ln1_b  = (const float*)d_in[3];
  const float* w_qkv  = (const float*)d_in[4];
  const float* q_bias = (const float*)d_in[5];
  const float* v_bias = (const float*)d_in[6];
  const float* w_proj = (const float*)d_in[7];
  const float* b_proj = (const float*)d_in[8];
  const float* gamma1 = (const float*)d_in[9];
  const float* gamma2 = (const float*)d_in[10];
  const float* ln2t_g = (const float*)d_in[11];
  const float* ln2t_b = (const float*)d_in[12];
  const float* ln2i_g = (const float*)d_in[13];
  const float* ln2i_b = (const float*)d_in[14];
  const float* wt1    = (const float*)d_in[15];
  const float* bt1    = (const float*)d_in[16];
  const float* wt2    = (const float*)d_in[17];
  const float* bt2    = (const float*)d_in[18];
  const float* wi1    = (const float*)d_in[19];
  const float* bi1    = (const float*)d_in[20];
  const float* wi2    = (const float*)d_in[21];
  const float* bi2    = (const float*)d_in[22];
  float* out = (float*)d_out;

  char* ws = (char*)d_ws;
  // byte offsets (all 256-aligned)
  bf16_t* wqkvb  = (bf16_t*)(ws + 0);            // 3,538,944
  bf16_t* wprojb = (bf16_t*)(ws + 3538944);      // 1,179,648
  bf16_t* wt1b   = (bf16_t*)(ws + 4718592);      // 4,718,592
  bf16_t* wi1b   = (bf16_t*)(ws + 9437184);
  bf16_t* wt2b   = (bf16_t*)(ws + 14155776);
  bf16_t* wi2b   = (bf16_t*)(ws + 18874368);
  bf16_t* n1     = (bf16_t*)(ws + 23592960);     // 15,138,816  (reused as n2p)
  float*  x1     = (float*) (ws + 38731776);     // 30,277,632
  bf16_t* qbuf   = (bf16_t*)(ws + 69009408);     // 15,728,640
  bf16_t* kbuf   = (bf16_t*)(ws + 84738048);     // 15,728,640
  bf16_t* vTbuf  = (bf16_t*)(ws + 100466688);    // 15,728,640
  bf16_t* o_mat  = (bf16_t*)(ws + 116195328);    // 15,138,816  -> end 131,334,144
  bf16_t* hbuf   = (bf16_t*)(ws + 69009408);     // 60,555,264 (reuses q/k/vT/o_mat after attn+proj)
  bf16_t* n2p    = n1;

  // 1. weights -> bf16
  cast_f32_bf16<<<1024, 256, 0, stream>>>(w_qkv,  wqkvb,  3 * C_ * C_);
  cast_f32_bf16<<<512,  256, 0, stream>>>(w_proj, wprojb, C_ * C_);
  cast_f32_bf16<<<1024, 256, 0, stream>>>(wt1, wt1b, HID * C_);
  cast_f32_bf16<<<1024, 256, 0, stream>>>(wi1, wi1b, HID * C_);
  cast_f32_bf16<<<1024, 256, 0, stream>>>(wt2, wt2b, C_ * HID);
  cast_f32_bf16<<<1024, 256, 0, stream>>>(wi2, wi2b, C_ * HID);
  // 2. zero q/k/vT (incl. seq pads -> masked softmax & P*V stay finite)
  zero_f4<<<2048, 256, 0, stream>>>((float4*)qbuf, (3 * 15728640) / 16);

  // 3. LN1 -> bf16
  ln_rows<<<M_ALL, 256, 0, stream>>>(x, ln1_g, ln1_b, n1);

  // 4. QKV GEMM
  {
    EpiP P{}; P.bias = q_bias; P.bias2 = v_bias;
    P.ob0 = qbuf; P.ob1 = kbuf; P.ob2 = vTbuf;
    gemm_bt<0><<<dim3(M_ALL / 128, (3 * C_) / 128), 256, 0, stream>>>(n1, wqkvb, C_, 3 * C_, P);
  }
  // 5. attention
  attn_fwd<<<dim3(NP / 64, B_ * H_), 256, 0, stream>>>(qbuf, kbuf, vTbuf, rel, o_mat);

  // 6. proj + residual -> x1 (f32)
  {
    EpiP P{}; P.bias = b_proj; P.gamma = gamma1; P.xres = x; P.outf = x1;
    gemm_bt<1><<<dim3(M_ALL / 128, C_ / 128), 256, 0, stream>>>(o_mat, wprojb, C_, C_, P);
  }
  // 7. LN2 + gather into packed text/image rows
  ln2_pack<<<M_ALL, 256, 0, stream>>>(x1, ln2t_g, ln2t_b, ln2i_g, ln2i_b, n2p);

  // 8. MLP fc1 + gelu  (text | image)
  {
    EpiP P{}; P.bias = bt1; P.ob0 = hbuf;
    gemm_bt<2><<<dim3(MT / 128, HID / 128), 256, 0, stream>>>(n2p, wt1b, C_, HID, P);
  }
  {
    EpiP P{}; P.bias = bi1; P.ob0 = hbuf + (size_t)MT * HID;
    gemm_bt<2><<<dim3(MI / 128, HID / 128), 256, 0, stream>>>(n2p + (size_t)MT * C_, wi1b, C_, HID, P);
  }
  // 9. MLP fc2 + gamma2 residual, scatter into d_out
  {
    EpiP P{}; P.bias = bt2; P.gamma = gamma2; P.xres = x1; P.outf = out;
    P.npb = NT; P.noff = 0;
    gemm_bt<3><<<dim3(MT / 128, C_ / 128), 256, 0, stream>>>(hbuf, wt2b, HID, C_, P);
  }
  {
    EpiP P{}; P.bias = bi2; P.gamma = gamma2; P.xres = x1; P.outf = out;
    P.npb = NI; P.noff = NT;
    gemm_bt<3><<<dim3(MI / 128, C_ / 128), 256, 0, stream>>>(hbuf + (size_t)MT * HID, wi2b, HID, C_, P);
  }
}

// Round 2
// 558.094 us; speedup vs baseline: 1.0922x; 1.0922x over previous
//
#include <hip/hip_runtime.h>
#include <hip/hip_bf16.h>
#include <stdint.h>
#include <math.h>

#define AS1 __attribute__((address_space(1)))
#define AS3 __attribute__((address_space(3)))

typedef __bf16 bf16_t;
typedef __bf16 bf16x8 __attribute__((ext_vector_type(8)));
typedef float f32x4 __attribute__((ext_vector_type(4)));

static constexpr int B_ = 16, N_ = 616, C_ = 768, H_ = 12, HD = 64, HID = 3072;
static constexpr int NP = 640;           // padded seq len for q/k/vT
static constexpr int M_REAL = B_ * N_;   // 9856
static constexpr int M_PAD = 9984;       // 39*256
static constexpr int NT_ = 40, NI_ = 576;

__device__ __forceinline__ void gl_lds16(const void* g, void* l) {
  __builtin_amdgcn_global_load_lds((const AS1 void*)(uintptr_t)g,
                                   (AS3 void*)(uint32_t)(uintptr_t)l, 16, 0, 0);
}
__device__ __forceinline__ f32x4 mfma16(bf16x8 a, bf16x8 b, f32x4 c) {
  return __builtin_amdgcn_mfma_f32_16x16x32_bf16(a, b, c, 0, 0, 0);
}
// gelu (erf) via tanh approx: 0.5x(1+tanh(0.79788456(x+0.044715x^3))) = x*sigmoid(2u)
__device__ __forceinline__ float gelu_f(float x) {
  float u = x * (0.7978845608f + 0.0356774081f * x * x);
  return x / (1.f + __expf(-2.f * u));
}

// ---------------------------------------------------------------- utilities
__global__ void cast_f32_bf16(const float* __restrict__ in, bf16_t* __restrict__ out, int n) {
  int i = blockIdx.x * blockDim.x + threadIdx.x;
  int st = gridDim.x * blockDim.x;
  for (; i < n; i += st) out[i] = (bf16_t)in[i];
}
__global__ void zero_f4(float4* __restrict__ p, int n4) {
  int i = blockIdx.x * blockDim.x + threadIdx.x;
  int st = gridDim.x * blockDim.x;
  float4 z = {0.f, 0.f, 0.f, 0.f};
  for (; i < n4; i += st) p[i] = z;
}

// ---------------------------------------------------------------- layernorms
__global__ __launch_bounds__(256) void ln_rows(const float* __restrict__ x,
                                               const float* __restrict__ g,
                                               const float* __restrict__ b,
                                               bf16_t* __restrict__ out) {
  int r = blockIdx.x, t = threadIdx.x;
  bf16_t* orow = out + (size_t)r * C_;
  if (r >= M_REAL) { orow[t] = (bf16_t)0.f; orow[t+256] = (bf16_t)0.f; orow[t+512] = (bf16_t)0.f; return; }
  const float* xr = x + (size_t)r * C_;
  float v0 = xr[t], v1 = xr[t + 256], v2 = xr[t + 512];
  float s = v0 + v1 + v2, ss = v0 * v0 + v1 * v1 + v2 * v2;
#pragma unroll
  for (int off = 32; off > 0; off >>= 1) { s += __shfl_xor(s, off); ss += __shfl_xor(ss, off); }
  __shared__ float sm[8];
  int w = t >> 6;
  if ((t & 63) == 0) { sm[w] = s; sm[4 + w] = ss; }
  __syncthreads();
  s = sm[0] + sm[1] + sm[2] + sm[3];
  ss = sm[4] + sm[5] + sm[6] + sm[7];
  float mean = s * (1.f / C_);
  float var = ss * (1.f / C_) - mean * mean;
  float ri = rsqrtf(var + 1e-5f);
  orow[t]       = (bf16_t)((v0 - mean) * ri * g[t]       + b[t]);
  orow[t + 256] = (bf16_t)((v1 - mean) * ri * g[t + 256] + b[t + 256]);
  orow[t + 512] = (bf16_t)((v2 - mean) * ri * g[t + 512] + b[t + 512]);
}

// LN2 + pack: packed rows [0,640)=text, [640,768)=zero pad, [768,9984)=image
__global__ __launch_bounds__(256) void ln2_pack(const float* __restrict__ x1,
                                                const float* __restrict__ gt, const float* __restrict__ bt,
                                                const float* __restrict__ gi, const float* __restrict__ bi,
                                                bf16_t* __restrict__ out) {
  int m = blockIdx.x, t = threadIdx.x;
  if (m >= M_REAL) {
    bf16_t* orow = out + (size_t)(640 + (m - M_REAL)) * C_;
    orow[t] = (bf16_t)0.f; orow[t+256] = (bf16_t)0.f; orow[t+512] = (bf16_t)0.f;
    return;
  }
  int b_ = m / N_, nn = m - b_ * N_;
  const float* g; const float* bb; int dest;
  if (nn < NT_) { dest = b_ * NT_ + nn; g = gt; bb = bt; }
  else          { dest = 768 + b_ * NI_ + (nn - NT_); g = gi; bb = bi; }
  const float* xr = x1 + (size_t)m * C_;
  float v0 = xr[t], v1 = xr[t + 256], v2 = xr[t + 512];
  float s = v0 + v1 + v2, ss = v0 * v0 + v1 * v1 + v2 * v2;
#pragma unroll
  for (int off = 32; off > 0; off >>= 1) { s += __shfl_xor(s, off); ss += __shfl_xor(ss, off); }
  __shared__ float sm[8];
  int w = t >> 6;
  if ((t & 63) == 0) { sm[w] = s; sm[4 + w] = ss; }
  __syncthreads();
  s = sm[0] + sm[1] + sm[2] + sm[3];
  ss = sm[4] + sm[5] + sm[6] + sm[7];
  float mean = s * (1.f / C_);
  float var = ss * (1.f / C_) - mean * mean;
  float ri = rsqrtf(var + 1e-5f);
  bf16_t* orow = out + (size_t)dest * C_;
  orow[t]       = (bf16_t)((v0 - mean) * ri * g[t]       + bb[t]);
  orow[t + 256] = (bf16_t)((v1 - mean) * ri * g[t + 256] + bb[t + 256]);
  orow[t + 512] = (bf16_t)((v2 - mean) * ri * g[t + 512] + bb[t + 512]);
}

// ---------------------------------------------------------------- v transpose
// vT[bh][d][0..640) <- v[bh][n<616][d], zero for n>=616
__global__ __launch_bounds__(256) void transpose_v(const bf16_t* __restrict__ v,
                                                   bf16_t* __restrict__ vT) {
  __shared__ bf16_t t[64][80];
  int n0 = blockIdx.x * 64, bh = blockIdx.y;
  int tid = threadIdx.x;
  int r0 = tid >> 2, c0 = (tid & 3) * 16;  // r0: n-local, c0: d base
  int n = n0 + r0;
#pragma unroll
  for (int cc = 0; cc < 2; ++cc) {
    bf16x8 vv;
    if (n < N_) vv = *(const bf16x8*)(v + ((size_t)bh * N_ + n) * HD + c0 + cc * 8);
    else {
#pragma unroll
      for (int e = 0; e < 8; ++e) vv[e] = (bf16_t)0.f;
    }
#pragma unroll
    for (int e = 0; e < 8; ++e) t[c0 + cc * 8 + e][r0] = vv[e];
  }
  __syncthreads();
  int d = tid >> 2, nc = (tid & 3) * 16;
  bf16_t* dst = vT + ((size_t)(bh * HD + d)) * NP + n0 + nc;
  *(bf16x8*)dst       = *(const bf16x8*)&t[d][nc];
  *(bf16x8*)(dst + 8) = *(const bf16x8*)&t[d][nc + 8];
}

// ---------------------------------------------------------------- GEMM 256x256, 8-phase
struct EpiP {
  const float* bias;    // col bias (text for EPI2/3)
  const float* bias_i;  // image col bias (EPI2/3)
  const float* bias2;   // v_bias (EPI0)
  const float* gamma;
  const float* xres;
  float* outf;
  bf16_t* ob0;
  bf16_t* ob1;
  bf16_t* ob2;
};

extern __shared__ char smem_raw[];

#define MFMA_QUAD(MH, NH, BV)                                                  \
  _Pragma("unroll") for (int i_ = 0; i_ < 4; ++i_)                             \
  _Pragma("unroll") for (int j_ = 0; j_ < 2; ++j_)                             \
  _Pragma("unroll") for (int kk_ = 0; kk_ < 2; ++kk_)                          \
    acc[(MH)*4 + i_][(NH)*2 + j_] =                                            \
        mfma16(av[i_][kk_], BV[j_][kk_], acc[(MH)*4 + i_][(NH)*2 + j_]);

#define LDA_FRAG(MH)                                                           \
  _Pragma("unroll") for (int i_ = 0; i_ < 4; ++i_)                             \
  _Pragma("unroll") for (int kk_ = 0; kk_ < 2; ++kk_) {                        \
    int R_ = wr * 128 + (MH)*64 + i_ * 16 + l16;                               \
    av[i_][kk_] = *(const bf16x8*)(AsS + R_ * 64 +                             \
                   ((kk_ * 32 + lq * 8) ^ ((R_ & 7) << 3))); }

#define LDB_FRAG(NH, BV)                                                       \
  _Pragma("unroll") for (int j_ = 0; j_ < 2; ++j_)                             \
  _Pragma("unroll") for (int kk_ = 0; kk_ < 2; ++kk_) {                        \
    int R_ = wc * 64 + (NH)*32 + j_ * 16 + l16;                                \
    BV[j_][kk_] = *(const bf16x8*)(BsS + R_ * 64 +                             \
                   ((kk_ * 32 + lq * 8) ^ ((R_ & 7) << 3))); }

template <int EPI>
__global__ __launch_bounds__(512, 2) void gemm256(const bf16_t* __restrict__ A,
                                                  const bf16_t* __restrict__ Bt,
                                                  const bf16_t* __restrict__ Bi,
                                                  int K, int tb, EpiP P) {
  bf16_t* As = (bf16_t*)smem_raw;          // [2][2048 granules]
  bf16_t* Bs = As + 32768;
  const int tid = threadIdx.x, lane = tid & 63, w = tid >> 6;
  const int l16 = lane & 15, lq = lane >> 4;
  const int wr = w >> 2, wc = w & 3;
  const int m0 = blockIdx.x * 256, n0 = blockIdx.y * 256;
  const bf16_t* Bw = (blockIdx.x < tb) ? Bt : Bi;
  const int NTt = K >> 6;

  f32x4 acc[8][4] = {};

  // stage one half-tile (16KB): A halves by row-bit6, B halves by row-bit5.
  // LDS stays linear; global source chunk is XOR-permuted (rule 21).
  auto stageA = [&](int slot, int half, int T) {
#pragma unroll
    for (int r = 0; r < 2; ++r) {
      int gb = r * 512 + w * 64;
      int g = gb + lane;
      int row = ((g >> 3) & 63) | (half << 6) | ((g >> 9) << 7);
      int cc = (g & 7) ^ ((g >> 3) & 7);
      gl_lds16(A + (size_t)(m0 + row) * K + T * 64 + cc * 8,
               As + slot * 16384 + (size_t)(w * 64 + r * 1024 + half * 512) * 8);
    }
  };
  auto stageB = [&](int slot, int half, int T) {
#pragma unroll
    for (int r = 0; r < 2; ++r) {
      int gb = r * 512 + w * 64;
      int g = gb + lane;
      int row = ((g >> 3) & 31) | (half << 5) | (((g >> 8) & 3) << 6);
      int cc = (g & 7) ^ ((g >> 3) & 7);
      gl_lds16(Bw + (size_t)(n0 + row) * K + T * 64 + cc * 8,
               Bs + slot * 16384 + (size_t)((gb & 255) + half * 256 + ((gb >> 8) & 3) * 512) * 8);
    }
  };

  // ---- prologue: T0 full (4 halves), T1 partial (3 halves; B-n0(T1) comes at T0.ph1)
  stageA(0, 0, 0); stageA(0, 1, 0); stageB(0, 0, 0); stageB(0, 1, 0);
  if (NTt > 1) {
    stageA(1, 0, 1); stageB(1, 1, 1); stageA(1, 1, 1);
    asm volatile("s_waitcnt vmcnt(6)" ::: "memory");
  } else {
    asm volatile("s_waitcnt vmcnt(0)" ::: "memory");
  }
  __builtin_amdgcn_s_barrier();

  for (int T = 0; T < NTt; ++T) {
    const int s = T & 1;
    const bf16_t* AsS = As + s * 16384;
    const bf16_t* BsS = Bs + s * 16384;
    bf16x8 av[4][2], bv0[2][2], bv1[2][2];

    // ---- ph1: quadrant (0,0)
    LDA_FRAG(0);
    LDB_FRAG(0, bv0);
    if (T + 1 < NTt) stageB(s ^ 1, 0, T + 1);
    __builtin_amdgcn_s_barrier();
    asm volatile("s_waitcnt lgkmcnt(0)" ::: "memory");
    __builtin_amdgcn_sched_barrier(0);
    __builtin_amdgcn_s_setprio(1);
    MFMA_QUAD(0, 0, bv0);
    __builtin_amdgcn_s_setprio(0);
    __builtin_amdgcn_s_barrier();

    // ---- ph2: quadrant (0,1)
    LDB_FRAG(1, bv1);
    if (T + 2 < NTt) stageA(s, 0, T + 2);
    __builtin_amdgcn_s_barrier();
    asm volatile("s_waitcnt lgkmcnt(0)" ::: "memory");
    __builtin_amdgcn_sched_barrier(0);
    __builtin_amdgcn_s_setprio(1);
    MFMA_QUAD(0, 1, bv1);
    __builtin_amdgcn_s_setprio(0);
    __builtin_amdgcn_s_barrier();

    // ---- ph3: quadrant (1,1)
    LDA_FRAG(1);
    if (T + 2 < NTt) stageB(s, 1, T + 2);
    __builtin_amdgcn_s_barrier();
    asm volatile("s_waitcnt lgkmcnt(0)" ::: "memory");
    __builtin_amdgcn_sched_barrier(0);
    __builtin_amdgcn_s_setprio(1);
    MFMA_QUAD(1, 1, bv1);
    __builtin_amdgcn_s_setprio(0);
    __builtin_amdgcn_s_barrier();

    // ---- ph4: quadrant (1,0)
    LDB_FRAG(0, bv0);
    if (T + 2 < NTt) stageA(s, 1, T + 2);
    __builtin_amdgcn_s_barrier();
    asm volatile("s_waitcnt lgkmcnt(0)" ::: "memory");
    __builtin_amdgcn_sched_barrier(0);
    __builtin_amdgcn_s_setprio(1);
    MFMA_QUAD(1, 0, bv0);
    __builtin_amdgcn_s_setprio(0);
    if (T + 2 < NTt) asm volatile("s_waitcnt vmcnt(6)" ::: "memory");
    else             asm volatile("s_waitcnt vmcnt(0)" ::: "memory");
    __builtin_amdgcn_s_barrier();
  }

  // ---- epilogue
  const float* bsel = (blockIdx.x < tb) ? P.bias : P.bias_i;
  (void)bsel;
  int which = n0 / C_;  // EPI0: block lies entirely in one third of 2304
#pragma unroll
  for (int im = 0; im < 8; ++im) {
    int mrow0 = m0 + wr * 128 + (im >> 2) * 64 + (im & 3) * 16 + lq * 4;
#pragma unroll
    for (int jn = 0; jn < 4; ++jn) {
      int jc = n0 + wc * 64 + (jn >> 1) * 32 + (jn & 1) * 16 + l16;
#pragma unroll
      for (int rr = 0; rr < 4; ++rr) {
        int m = mrow0 + rr;
        float v = acc[im][jn][rr];
        if constexpr (EPI == 0) {       // QKV split; q,k -> [bh][640][64], v -> [bh][616][64]
          if (m < M_REAL) {
            int b_ = m / N_, nn = m - b_ * N_;
            int jj = jc - which * C_;
            int hh = jj >> 6, d = jj & 63;
            int bh = b_ * H_ + hh;
            if (which == 0) {
              P.ob0[((size_t)bh * NP + nn) * HD + d] = (bf16_t)((v + P.bias[jj]) * 0.125f);
            } else if (which == 1) {
              P.ob1[((size_t)bh * NP + nn) * HD + d] = (bf16_t)v;
            } else {
              P.ob2[((size_t)bh * N_ + nn) * HD + d] = (bf16_t)(v + P.bias2[jj]);
            }
          }
        } else if constexpr (EPI == 1) {  // proj: x1 = x + gamma1*(o+b)
          if (m < M_REAL) {
            size_t idx = (size_t)m * C_ + jc;
            P.outf[idx] = P.xres[idx] + P.gamma[jc] * (v + P.bias[jc]);
          }
        } else if constexpr (EPI == 2) {  // mlp1: gelu -> hbuf (pads included, finite)
          P.ob0[(size_t)m * HID + jc] = (bf16_t)gelu_f(v + bsel[jc]);
        } else {                          // mlp2: residual scatter to d_out
          int orig = -1;
          if (m < 640)      orig = (m / NT_) * N_ + (m - (m / NT_) * NT_);
          else if (m >= 768) {
            int mi = m - 768;
            int bb = mi / NI_;
            orig = bb * N_ + NT_ + (mi - bb * NI_);
          }
          if (orig >= 0) {
            size_t idx = (size_t)orig * C_ + jc;
            P.outf[idx] = P.xres[idx] + P.gamma[jc] * (v + bsel[jc]);
          }
        }
      }
    }
  }
}

// ---------------------------------------------------------------- attention (round-1, validated)
__global__ __launch_bounds__(256) void attn_fwd(const bf16_t* __restrict__ qb,
                                                const bf16_t* __restrict__ kb,
                                                const bf16_t* __restrict__ vT,
                                                const float* __restrict__ rel_bias,
                                                bf16_t* __restrict__ o_mat) {
  __shared__ bf16_t qs[64 * 64], ks[64 * 64], vs[64 * 64];
  __shared__ bf16_t ps[4][16 * 64];
  const int tid = threadIdx.x, lane = tid & 63, w = tid >> 6;
  const int l16 = lane & 15, lq = lane >> 4;
  const int qt = blockIdx.x, bh = blockIdx.y;
  const int b_ = bh / H_, h = bh - b_ * H_;
  const int q0 = qt * 64;

  const bf16_t* qsrc = qb + ((size_t)bh * NP + q0) * HD;
#pragma unroll
  for (int it = 0; it < 2; ++it) {
    int cb = it * 256 + w * 64, c = cb + lane;
    gl_lds16(qsrc + c * 8, qs + cb * 8);
  }
  __syncthreads();
  bf16x8 aq[2];
  aq[0] = *(const bf16x8*)(qs + (w * 16 + l16) * 64 + 0 + lq * 8);
  aq[1] = *(const bf16x8*)(qs + (w * 16 + l16) * 64 + 32 + lq * 8);

  float mrun[4], lrun[4];
  f32x4 oacc[4] = {};
#pragma unroll
  for (int r = 0; r < 4; ++r) { mrun[r] = -3e38f; lrun[r] = 0.f; }

  const int qrow_base = q0 + w * 16 + lq * 4;
  const float* biasr = rel_bias + (size_t)h * N_ * N_;

  for (int kt = 0; kt < NP / 64; ++kt) {
    int n0k = kt * 64;
    const bf16_t* ksrc = kb + ((size_t)bh * NP + n0k) * HD;
#pragma unroll
    for (int it = 0; it < 2; ++it) {
      int cb = it * 256 + w * 64, c = cb + lane;
      gl_lds16(ksrc + c * 8, ks + cb * 8);
      int d = c >> 3, kc = (c & 7) << 3;
      gl_lds16(vT + ((size_t)bh * HD + d) * NP + n0k + kc, vs + cb * 8);
    }
    __syncthreads();

    f32x4 sf[4];
#pragma unroll
    for (int f = 0; f < 4; ++f) {
      f32x4 z = {};
#pragma unroll
      for (int kk = 0; kk < 2; ++kk) {
        bf16x8 bk = *(const bf16x8*)(ks + (f * 16 + l16) * 64 + kk * 32 + lq * 8);
        z = mfma16(aq[kk], bk, z);
      }
      sf[f] = z;
    }
    float pm[4];
#pragma unroll
    for (int r = 0; r < 4; ++r) pm[r] = -3e38f;
#pragma unroll
    for (int f = 0; f < 4; ++f) {
      int kcol = n0k + f * 16 + l16;
#pragma unroll
      for (int r = 0; r < 4; ++r) {
        int qg = qrow_base + r;
        int qc = qg < N_ ? qg : (N_ - 1);
        float sv = (kcol < N_) ? (sf[f][r] + biasr[(size_t)qc * N_ + kcol]) : -3e38f;
        sf[f][r] = sv;
        pm[r] = fmaxf(pm[r], sv);
      }
    }
#pragma unroll
    for (int off = 1; off < 16; off <<= 1)
#pragma unroll
      for (int r = 0; r < 4; ++r)
        pm[r] = fmaxf(pm[r], __shfl_xor(pm[r], off, 16));

    float alpha[4], lsum[4];
#pragma unroll
    for (int r = 0; r < 4; ++r) {
      float mnew = fmaxf(mrun[r], pm[r]);
      alpha[r] = __expf(mrun[r] - mnew);
      mrun[r] = mnew;
      lsum[r] = 0.f;
    }
#pragma unroll
    for (int f = 0; f < 4; ++f)
#pragma unroll
      for (int r = 0; r < 4; ++r) {
        float p = __expf(sf[f][r] - mrun[r]);
        sf[f][r] = p;
        lsum[r] += p;
      }
#pragma unroll
    for (int off = 1; off < 16; off <<= 1)
#pragma unroll
      for (int r = 0; r < 4; ++r)
        lsum[r] += __shfl_xor(lsum[r], off, 16);
#pragma unroll
    for (int r = 0; r < 4; ++r) lrun[r] = lrun[r] * alpha[r] + lsum[r];
#pragma unroll
    for (int df = 0; df < 4; ++df)
#pragma unroll
      for (int r = 0; r < 4; ++r) oacc[df][r] *= alpha[r];

    bf16_t* psw = ps[w];
#pragma unroll
    for (int f = 0; f < 4; ++f)
#pragma unroll
      for (int r = 0; r < 4; ++r)
        psw[(lq * 4 + r) * 64 + f * 16 + l16] = (bf16_t)sf[f][r];
    __syncthreads();

#pragma unroll
    for (int kk = 0; kk < 2; ++kk) {
      bf16x8 pa = *(const bf16x8*)(psw + l16 * 64 + kk * 32 + lq * 8);
#pragma unroll
      for (int df = 0; df < 4; ++df) {
        bf16x8 bv = *(const bf16x8*)(vs + (df * 16 + l16) * 64 + kk * 32 + lq * 8);
        oacc[df] = mfma16(pa, bv, oacc[df]);
      }
    }
    __syncthreads();
  }

#pragma unroll
  for (int r = 0; r < 4; ++r) {
    int qg = qrow_base + r;
    if (qg < N_) {
      float rl = 1.f / lrun[r];
      size_t orow = ((size_t)(b_ * N_ + qg)) * C_ + h * HD;
#pragma unroll
      for (int df = 0; df < 4; ++df)
        o_mat[orow + df * 16 + l16] = (bf16_t)(oacc[df][r] * rl);
    }
  }
}

// ---------------------------------------------------------------- launch
extern "C" void kernel_launch(void* const* d_in, const int* in_sizes, int n_in,
                              void* d_out, int out_size, void* d_ws, size_t ws_size,
                              hipStream_t stream) {
  const float* x      = (const float*)d_in[0];
  const float* rel    = (const float*)d_in[1];
  const float* ln1_g  = (const float*)d_in[2];
  const float* ln1_b  = (const float*)d_in[3];
  const float* w_qkv  = (const float*)d_in[4];
  const float* q_bias = (const float*)d_in[5];
  const float* v_bias = (const float*)d_in[6];
  const float* w_proj = (const float*)d_in[7];
  const float* b_proj = (const float*)d_in[8];
  const float* gamma1 = (const float*)d_in[9];
  const float* gamma2 = (const float*)d_in[10];
  const float* ln2t_g = (const float*)d_in[11];
  const float* ln2t_b = (const float*)d_in[12];
  const float* ln2i_g = (const float*)d_in[13];
  const float* ln2i_b = (const float*)d_in[14];
  const float* wt1    = (const float*)d_in[15];
  const float* bt1    = (const float*)d_in[16];
  const float* wt2    = (const float*)d_in[17];
  const float* bt2    = (const float*)d_in[18];
  const float* wi1    = (const float*)d_in[19];
  const float* bi1    = (const float*)d_in[20];
  const float* wi2    = (const float*)d_in[21];
  const float* bi2    = (const float*)d_in[22];
  float* out = (float*)d_out;

  char* ws = (char*)d_ws;
  // layout (bytes):
  bf16_t* wqkvb  = (bf16_t*)(ws + 0);           //  3,538,944
  bf16_t* wprojb = (bf16_t*)(ws + 3538944);     //  1,179,648
  bf16_t* wt1b   = (bf16_t*)(ws + 4718592);     //  4,718,592
  bf16_t* wi1b   = (bf16_t*)(ws + 9437184);
  bf16_t* wt2b   = (bf16_t*)(ws + 14155776);
  bf16_t* wi2b   = (bf16_t*)(ws + 18874368);
  bf16_t* n1     = (bf16_t*)(ws + 23592960);    // 15,335,424 (9984x768) — also n2p, o_mat
  float*  x1     = (float*) (ws + 38928384);    // 30,277,632 — first 15.1MB doubles as vtmp
  bf16_t* qbuf   = (bf16_t*)(ws + 69206016);    // 15,728,640
  bf16_t* kbuf   = (bf16_t*)(ws + 84934656);    // 15,728,640
  bf16_t* vTbuf  = (bf16_t*)(ws + 100663296);   // 15,728,640 -> end 116,391,936
  bf16_t* vtmp   = (bf16_t*)(ws + 38928384);    // [bh][616][64]
  bf16_t* o_mat  = n1;                          // reuses n1 region after QKV
  bf16_t* n2p    = n1;
  bf16_t* hbuf   = qbuf;                        // 61,341,696 over q/k/vT (dead) -> 130,547,712

  // allow 128KB dynamic LDS on the gemm instantiations (host-side, capture-safe)
  hipFuncSetAttribute((const void*)gemm256<0>, hipFuncAttributeMaxDynamicSharedMemorySize, 131072);
  hipFuncSetAttribute((const void*)gemm256<1>, hipFuncAttributeMaxDynamicSharedMemorySize, 131072);
  hipFuncSetAttribute((const void*)gemm256<2>, hipFuncAttributeMaxDynamicSharedMemorySize, 131072);
  hipFuncSetAttribute((const void*)gemm256<3>, hipFuncAttributeMaxDynamicSharedMemorySize, 131072);

  // 1. weights -> bf16
  cast_f32_bf16<<<1024, 256, 0, stream>>>(w_qkv,  wqkvb,  3 * C_ * C_);
  cast_f32_bf16<<<512,  256, 0, stream>>>(w_proj, wprojb, C_ * C_);
  cast_f32_bf16<<<1024, 256, 0, stream>>>(wt1, wt1b, HID * C_);
  cast_f32_bf16<<<1024, 256, 0, stream>>>(wi1, wi1b, HID * C_);
  cast_f32_bf16<<<1024, 256, 0, stream>>>(wt2, wt2b, C_ * HID);
  cast_f32_bf16<<<1024, 256, 0, stream>>>(wi2, wi2b, C_ * HID);
  // 2. zero q/k/vT (47.2MB contiguous) so seq pads are finite-zero
  zero_f4<<<2048, 256, 0, stream>>>((float4*)qbuf, 47185920 / 16);
  // 3. LN1 (pads -> zero rows)
  ln_rows<<<M_PAD, 256, 0, stream>>>(x, ln1_g, ln1_b, n1);
  // 4. QKV GEMM (v row-major into vtmp)
  {
    EpiP P{}; P.bias = q_bias; P.bias2 = v_bias;
    P.ob0 = qbuf; P.ob1 = kbuf; P.ob2 = vtmp;
    gemm256<0><<<dim3(M_PAD / 256, (3 * C_) / 256), 512, 131072, stream>>>(n1, wqkvb, wqkvb, C_, 0, P);
  }
  // 5. v transpose (writes full vT incl. zero pads)
  transpose_v<<<dim3(NP / 64, B_ * H_), 256, 0, stream>>>(vtmp, vTbuf);
  // 6. attention -> o_mat (n1 region; n1 dead now)
  attn_fwd<<<dim3(NP / 64, B_ * H_), 256, 0, stream>>>(qbuf, kbuf, vTbuf, rel, o_mat);
  // 7. zero o_mat pad rows [9856,9984)
  zero_f4<<<64, 256, 0, stream>>>((float4*)(ws + 38731776), 196608 / 16);
  // 8. proj + residual -> x1 (overwrites vtmp, dead)
  {
    EpiP P{}; P.bias = b_proj; P.bias_i = b_proj; P.gamma = gamma1; P.xres = x; P.outf = x1;
    gemm256<1><<<dim3(M_PAD / 256, C_ / 256), 512, 131072, stream>>>(o_mat, wprojb, wprojb, C_, 0, P);
  }
  // 9. LN2 + pack (overwrites o_mat region, dead)
  ln2_pack<<<M_PAD, 256, 0, stream>>>(x1, ln2t_g, ln2t_b, ln2i_g, ln2i_b, n2p);
  // 10. MLP fc1 + gelu (text blocks 0-2, image 3-38) -> hbuf
  {
    EpiP P{}; P.bias = bt1; P.bias_i = bi1; P.ob0 = hbuf;
    gemm256<2><<<dim3(M_PAD / 256, HID / 256), 512, 131072, stream>>>(n2p, wt1b, wi1b, C_, 3, P);
  }
  // 11. MLP fc2 + gamma2 residual -> d_out
  {
    EpiP P{}; P.bias = bt2; P.bias_i = bi2; P.gamma = gamma2; P.xres = x1; P.outf = out;
    gemm256<3><<<dim3(M_PAD / 256, C_ / 256), 512, 131072, stream>>>(hbuf, wt2b, wi2b, HID, 3, P);
  }
}